// Round 5
// baseline (419.808 us; speedup 1.0000x reference)
//
#include <hip/hip_runtime.h>

#define NN 100000
#define NREG 8
#define RSPAN ((NN + NREG - 1) / NREG)  // 12500

typedef __attribute__((ext_vector_type(8))) short short8;
typedef __attribute__((ext_vector_type(4))) float f32x4;

__device__ __forceinline__ unsigned short f2bf(float f) {
  union { float f; unsigned int u; } v;
  v.f = f;
  unsigned int r = (v.u + 0x7fffu + ((v.u >> 16) & 1u)) >> 16;  // RNE
  return (unsigned short)r;
}
__device__ __forceinline__ float bf2f(unsigned short u) {
  union { unsigned int u; float f; } v;
  v.u = ((unsigned int)u) << 16;
  return v.f;
}

// ---------- degree count (int) ----------
__global__ void k_deg(const int* __restrict__ dst, int E, int* __restrict__ cnt) {
  int i = blockIdx.x * blockDim.x + threadIdx.x;
  if (i < E) atomicAdd(&cnt[dst[i]], 1);
}

// ---------- per-region edge totals (for contiguous region zones in bin) ----------
__global__ __launch_bounds__(256) void k_rsize(const int* __restrict__ cnt,
                                               int* __restrict__ rsize, int n) {
  int i = blockIdx.x * 256 + threadIdx.x;
  int c = (i < n) ? cnt[i] : 0;
  int r = min(i, n - 1) / RSPAN;
  int lane = threadIdx.x & 63;
  int r0 = __shfl(r, 0), r63 = __shfl(r, 63);
  if (r0 == r63) {  // wave entirely within one region (common case)
    int s = c;
#pragma unroll
    for (int off = 32; off > 0; off >>= 1) s += __shfl_down(s, off);
    if (lane == 0 && s) atomicAdd(&rsize[r0], s);
  } else {
    if (i < n && c) atomicAdd(&rsize[r], c);
  }
}

// ---------- allocator: region-contiguous segment offsets + dinv ----------
// Region r's segments occupy bin[rbase(r) .. rbase(r)+rsize[r]); within a
// region, waves grab space atomically (order irrelevant).
__global__ __launch_bounds__(256) void k_alloc(const int* __restrict__ cnt,
                                               int* __restrict__ ofs,
                                               float* __restrict__ dinv,
                                               const int* __restrict__ rsize,
                                               int* __restrict__ rtotal, int n) {
  int i = blockIdx.x * 256 + threadIdx.x;
  int c = (i < n) ? cnt[i] : 0;
  if (i < n) dinv[i] = rsqrtf((float)c + 1.0f);  // +1 self-loop
  const int lane = threadIdx.x & 63;
  int r = min(i, n - 1) / RSPAN;
  int rbase = 0;
#pragma unroll
  for (int j = 0; j < NREG; ++j) rbase += (j < r) ? rsize[j] : 0;
  int incl = c;
#pragma unroll
  for (int off = 1; off < 64; off <<= 1) {
    int v = __shfl_up(incl, off);
    if (lane >= off) incl += v;
  }
  int r0 = __shfl(r, 0), r63 = __shfl(r, 63);
  if (r0 == r63) {
    int wavesum = __shfl(incl, 63);
    int base = 0;
    if (lane == 0) base = atomicAdd(&rtotal[r0], wavesum);
    base = __shfl(base, 0);
    if (i < n) ofs[i] = rbase + base + incl - c;
  } else {  // boundary wave: per-lane allocation
    if (i < n) ofs[i] = rbase + atomicAdd(&rtotal[r], c);
  }
}

// ---------- region-partitioned CSR fill ----------
// blocks with blockIdx%8==r handle only dst in region r; region zones in bin
// are written by one blockIdx%8 class (= one XCD under round-robin dispatch),
// so lines are packed and written back once instead of 64B per 4B store.
__global__ __launch_bounds__(256) void k_binfill2(const int* __restrict__ src,
                                                  const int* __restrict__ dst, int E,
                                                  const int* __restrict__ ofs,
                                                  int* __restrict__ cursor,
                                                  int* __restrict__ bin) {
  const int r = blockIdx.x & 7;
  const int sub = blockIdx.x >> 3;
  const int nsub = gridDim.x >> 3;
  const int lo = r * RSPAN, hi = min(lo + RSPAN, NN);
  for (int e = sub * 256 + threadIdx.x; e < E; e += nsub * 256) {
    int d = dst[e];
    if (d >= lo && d < hi) {
      int pos = atomicAdd(&cursor[d], 1);
      bin[ofs[d] + pos] = src[e];
    }
  }
}

// ---------- W1 [128,128] fp32 -> Btg [n][k] bf16 (transposed) ----------
__global__ void k_wprep(const float* __restrict__ W1, unsigned short* __restrict__ Btg) {
  int e = blockIdx.x * blockDim.x + threadIdx.x;  // 0..16383
  int n = e >> 7, k = e & 127;
  Btg[e] = f2bf(W1[k * 128 + n]);
}

// ---------- hA16 = bf16(x @ W1) via MFMA 16x16x32 ----------
__global__ __launch_bounds__(256) void k_gemm1(const float* __restrict__ x,
                                               const unsigned short* __restrict__ Btg,
                                               unsigned short* __restrict__ hA16,
                                               int N) {
  __shared__ __align__(16) unsigned short Bs[128][136];
  const int t = threadIdx.x;
#pragma unroll
  for (int it = 0; it < 8; ++it) {
    int idx = t + it * 256;
    int n = idx >> 4, c = (idx & 15) * 8;
    *(uint4*)&Bs[n][c] = *(const uint4*)&Btg[n * 128 + c];
  }
  __syncthreads();

  const int lane = t & 63, w = t >> 6;
  const int m = lane & 15, q = lane >> 4;
  const int grow = blockIdx.x * 64 + w * 16 + m;
  const bool valid = grow < N;
  const float* xp = &x[(size_t)(valid ? grow : 0) * 128];

  f32x4 acc[8];
#pragma unroll
  for (int nt = 0; nt < 8; ++nt) acc[nt] = (f32x4){0.f, 0.f, 0.f, 0.f};

#pragma unroll
  for (int ks = 0; ks < 4; ++ks) {
    short8 a;
    if (valid) {
      const float* p = xp + ks * 32 + q * 8;
      float4 f0 = *(const float4*)p;
      float4 f1 = *(const float4*)(p + 4);
      a[0] = (short)f2bf(f0.x); a[1] = (short)f2bf(f0.y);
      a[2] = (short)f2bf(f0.z); a[3] = (short)f2bf(f0.w);
      a[4] = (short)f2bf(f1.x); a[5] = (short)f2bf(f1.y);
      a[6] = (short)f2bf(f1.z); a[7] = (short)f2bf(f1.w);
    } else {
      a = (short8)0;
    }
#pragma unroll
    for (int nt = 0; nt < 8; ++nt) {
      short8 b = *(const short8*)&Bs[nt * 16 + m][ks * 32 + q * 8];
      acc[nt] = __builtin_amdgcn_mfma_f32_16x16x32_bf16(a, b, acc[nt], 0, 0, 0);
    }
  }

  const int orow = blockIdx.x * 64 + w * 16 + q * 4;
#pragma unroll
  for (int nt = 0; nt < 8; ++nt) {
    int col = nt * 16 + m;
#pragma unroll
    for (int rg = 0; rg < 4; ++rg) {
      int rr = orow + rg;
      if (rr < N) hA16[(size_t)rr * 128 + col] = f2bf(acc[nt][rg]);
    }
  }
}

// ---------- fused layer-1: CSR gather (bf16 hA) + self-loop + bias + relu + @W2 ----
__global__ __launch_bounds__(256) void k_gather1(const int* __restrict__ ofs,
                                                 const int* __restrict__ cnt,
                                                 const int* __restrict__ bin,
                                                 const float* __restrict__ dinv,
                                                 const unsigned int* __restrict__ hA,
                                                 const float* __restrict__ b1,
                                                 const float* __restrict__ W2,
                                                 float* __restrict__ t2base, int N) {
  int d = blockIdx.x * 4 + (threadIdx.x >> 6);
  if (d >= N) return;
  const int lane = threadIdx.x & 63;
  const int beg = ofs[d], end = beg + cnt[d];
  float ax = 0.f, ay = 0.f;
  int e = beg;
  for (; e + 7 < end; e += 8) {  // 8 loads in flight
    int s0 = bin[e],     s1 = bin[e + 1], s2 = bin[e + 2], s3 = bin[e + 3];
    int s4 = bin[e + 4], s5 = bin[e + 5], s6 = bin[e + 6], s7 = bin[e + 7];
    float w0 = dinv[s0], w1 = dinv[s1], w2 = dinv[s2], w3 = dinv[s3];
    float w4 = dinv[s4], w5 = dinv[s5], w6 = dinv[s6], w7 = dinv[s7];
    unsigned int v0 = hA[(size_t)s0 * 64 + lane];
    unsigned int v1 = hA[(size_t)s1 * 64 + lane];
    unsigned int v2 = hA[(size_t)s2 * 64 + lane];
    unsigned int v3 = hA[(size_t)s3 * 64 + lane];
    unsigned int v4 = hA[(size_t)s4 * 64 + lane];
    unsigned int v5 = hA[(size_t)s5 * 64 + lane];
    unsigned int v6 = hA[(size_t)s6 * 64 + lane];
    unsigned int v7 = hA[(size_t)s7 * 64 + lane];
    ax += w0 * bf2f(v0 & 0xffff) + w1 * bf2f(v1 & 0xffff) +
          w2 * bf2f(v2 & 0xffff) + w3 * bf2f(v3 & 0xffff) +
          w4 * bf2f(v4 & 0xffff) + w5 * bf2f(v5 & 0xffff) +
          w6 * bf2f(v6 & 0xffff) + w7 * bf2f(v7 & 0xffff);
    ay += w0 * bf2f(v0 >> 16) + w1 * bf2f(v1 >> 16) +
          w2 * bf2f(v2 >> 16) + w3 * bf2f(v3 >> 16) +
          w4 * bf2f(v4 >> 16) + w5 * bf2f(v5 >> 16) +
          w6 * bf2f(v6 >> 16) + w7 * bf2f(v7 >> 16);
  }
  for (; e < end; ++e) {
    int s = bin[e];
    float w = dinv[s];
    unsigned int v = hA[(size_t)s * 64 + lane];
    ax += w * bf2f(v & 0xffff);
    ay += w * bf2f(v >> 16);
  }
  const float dd = dinv[d];
  unsigned int vs = hA[(size_t)d * 64 + lane];
  float v0 = ax * dd + bf2f(vs & 0xffff) * dd * dd + b1[lane * 2];
  float v1 = ay * dd + bf2f(vs >> 16) * dd * dd + b1[lane * 2 + 1];
  v0 = fmaxf(v0, 0.f);
  v1 = fmaxf(v1, 0.f);
  float4 w2v = *(const float4*)&W2[lane * 4];
  float p0 = v0 * w2v.x + v1 * w2v.z;
  float p1 = v0 * w2v.y + v1 * w2v.w;
#pragma unroll
  for (int off = 32; off > 0; off >>= 1) {
    p0 += __shfl_down(p0, off);
    p1 += __shfl_down(p1, off);
  }
  if (lane == 0) *(float2*)&t2base[d * 2] = make_float2(p0, p1);
}

// ---------- fused final: layer-2 CSR gather + self-loop + b2 + x@W_skip + b_skip ----
__global__ __launch_bounds__(256) void k_final(const float* __restrict__ x,
                                               const float* __restrict__ W_skip,
                                               const float* __restrict__ b_skip,
                                               const float* __restrict__ b2,
                                               const float* __restrict__ t2base,
                                               const float* __restrict__ dinv,
                                               const int* __restrict__ ofs,
                                               const int* __restrict__ cnt,
                                               const int* __restrict__ bin,
                                               float* __restrict__ out, int N) {
  int i = blockIdx.x * 4 + (threadIdx.x >> 6);
  if (i >= N) return;
  const int lane = threadIdx.x & 63;
  float2 xv = *(const float2*)&x[(size_t)i * 128 + lane * 2];
  float4 wv = *(const float4*)&W_skip[lane * 4];
  float a0 = xv.x * wv.x + xv.y * wv.z;
  float a1 = xv.x * wv.y + xv.y * wv.w;
  const int beg = ofs[i], end = beg + cnt[i];
  float g0 = 0.f, g1 = 0.f;
  for (int e = beg + lane; e < end; e += 64) {
    int s = bin[e];
    float w = dinv[s];
    float2 t = *(const float2*)&t2base[s * 2];
    g0 += w * t.x; g1 += w * t.y;
  }
#pragma unroll
  for (int off = 32; off > 0; off >>= 1) {
    a0 += __shfl_down(a0, off);
    a1 += __shfl_down(a1, off);
    g0 += __shfl_down(g0, off);
    g1 += __shfl_down(g1, off);
  }
  if (lane == 0) {
    float di = dinv[i], d2 = di * di;
    float2 ts = *(const float2*)&t2base[i * 2];
    float o0 = g0 * di + ts.x * d2 + b2[0] + a0 + b_skip[0];
    float o1 = g1 * di + ts.y * d2 + b2[1] + a1 + b_skip[1];
    *(float2*)&out[i * 2] = make_float2(o0, o1);
  }
}

extern "C" void kernel_launch(void* const* d_in, const int* in_sizes, int n_in,
                              void* d_out, int out_size, void* d_ws, size_t ws_size,
                              hipStream_t stream) {
  const float* x      = (const float*)d_in[0];
  const int*   edges  = (const int*)d_in[1];
  const float* W1     = (const float*)d_in[2];
  const float* b1     = (const float*)d_in[3];
  const float* W2     = (const float*)d_in[4];
  const float* b2     = (const float*)d_in[5];
  const float* W_skip = (const float*)d_in[6];
  const float* b_skip = (const float*)d_in[7];
  float* out = (float*)d_out;

  const int N = NN;
  const int E = in_sizes[1] / 2;
  const int* src = edges;
  const int* dst = edges + E;

  // ws: [cnt N][cursor N][rsize 8][rtotal 8][ofs N+4][dinv N][bin E][t2base 2N]
  //     [Btg 16384][hA16 128N]
  int*   cnt    = (int*)d_ws;
  int*   cursor = cnt + N;
  int*   rsize  = cursor + N;
  int*   rtotal = rsize + NREG;
  int*   ofs    = rtotal + NREG;
  float* dinv   = (float*)(ofs + N + 4);
  int*   bin    = (int*)(dinv + N);
  float* t2base = (float*)(bin + E);
  unsigned short* Btg  = (unsigned short*)(t2base + 2 * (size_t)N);
  unsigned short* hA16 = Btg + 16384;

  // zero cnt + cursor + rsize + rtotal
  hipMemsetAsync(cnt, 0, (2 * (size_t)N + 2 * NREG) * sizeof(int), stream);

  k_wprep<<<64, 256, 0, stream>>>(W1, Btg);
  k_deg<<<(E + 255) / 256, 256, 0, stream>>>(dst, E, cnt);
  k_rsize<<<(N + 255) / 256, 256, 0, stream>>>(cnt, rsize, N);
  k_alloc<<<(N + 255) / 256, 256, 0, stream>>>(cnt, ofs, dinv, rsize, rtotal, N);
  k_binfill2<<<1024, 256, 0, stream>>>(src, dst, E, ofs, cursor, bin);
  k_gemm1<<<(N + 63) / 64, 256, 0, stream>>>(x, Btg, hA16, N);
  k_gather1<<<(N + 3) / 4, 256, 0, stream>>>(ofs, cnt, bin, dinv,
                                             (const unsigned int*)hA16, b1, W2,
                                             t2base, N);
  k_final<<<(N + 3) / 4, 256, 0, stream>>>(x, W_skip, b_skip, b2, t2base, dinv, ofs,
                                           cnt, bin, out, N);
}

// Round 6
// 414.225 us; speedup vs baseline: 1.0135x; 1.0135x over previous
//
#include <hip/hip_runtime.h>

#define NN 100000
#define NREG 8
#define RSPAN ((NN + NREG - 1) / NREG)  // 12500

typedef __attribute__((ext_vector_type(8))) short short8;
typedef __attribute__((ext_vector_type(4))) float f32x4;

__device__ __forceinline__ unsigned short f2bf(float f) {
  union { float f; unsigned int u; } v;
  v.f = f;
  unsigned int r = (v.u + 0x7fffu + ((v.u >> 16) & 1u)) >> 16;  // RNE
  return (unsigned short)r;
}
__device__ __forceinline__ float bf2f(unsigned short u) {
  union { unsigned int u; float f; } v;
  v.u = ((unsigned int)u) << 16;
  return v.f;
}

// ---------- degree count (int4-vectorized) ----------
__global__ void k_deg(const int* __restrict__ dst, int E, int* __restrict__ cnt) {
  int i = blockIdx.x * blockDim.x + threadIdx.x;
  int e4 = i * 4;
  if (e4 + 3 < E) {
    int4 d = *(const int4*)&dst[e4];
    atomicAdd(&cnt[d.x], 1);
    atomicAdd(&cnt[d.y], 1);
    atomicAdd(&cnt[d.z], 1);
    atomicAdd(&cnt[d.w], 1);
  } else {
    for (int e = e4; e < E; ++e) atomicAdd(&cnt[dst[e]], 1);
  }
}

// ---------- allocator: one atomic per block, consecutive nodes -> consecutive ofs.
// Regions are contiguous node ranges, so bin cache lines end up region-pure
// (except rare block-boundary lines) -> partitioned binfill gets write locality.
// Also computes dinv and zeroes cursor.
__global__ __launch_bounds__(256) void k_alloc(const int* __restrict__ cnt,
                                               int* __restrict__ ofs,
                                               float* __restrict__ dinv,
                                               int* __restrict__ cursor,
                                               int* __restrict__ total, int n) {
  int i = blockIdx.x * 256 + threadIdx.x;
  int c = (i < n) ? cnt[i] : 0;
  if (i < n) {
    dinv[i] = rsqrtf((float)c + 1.0f);  // +1 self-loop
    cursor[i] = 0;
  }
  const int lane = threadIdx.x & 63;
  const int wid = threadIdx.x >> 6;
  int incl = c;
#pragma unroll
  for (int off = 1; off < 64; off <<= 1) {
    int v = __shfl_up(incl, off);
    if (lane >= off) incl += v;
  }
  __shared__ int wsum[4];
  __shared__ int base;
  if (lane == 63) wsum[wid] = incl;
  __syncthreads();
  if (threadIdx.x == 0) {
    int s0 = wsum[0], s1 = wsum[1], s2 = wsum[2], s3 = wsum[3];
    base = atomicAdd(total, s0 + s1 + s2 + s3);
    wsum[0] = 0; wsum[1] = s0; wsum[2] = s0 + s1; wsum[3] = s0 + s1 + s2;
  }
  __syncthreads();
  if (i < n) ofs[i] = base + wsum[wid] + incl - c;
}

// ---------- region-partitioned CSR fill (blockIdx%8 == node region) ----------
__global__ __launch_bounds__(256) void k_binfill2(const int* __restrict__ src,
                                                  const int* __restrict__ dst, int E,
                                                  const int* __restrict__ ofs,
                                                  int* __restrict__ cursor,
                                                  int* __restrict__ bin) {
  const int r = blockIdx.x & 7;
  const int sub = blockIdx.x >> 3;
  const int nsub = gridDim.x >> 3;
  const int lo = r * RSPAN, hi = min(lo + RSPAN, NN);
  const int E4 = E >> 2;
  for (int i = sub * 256 + threadIdx.x; i < E4; i += nsub * 256) {
    int4 d4 = *(const int4*)&dst[i * 4];
    if (d4.x >= lo && d4.x < hi) {
      int pos = atomicAdd(&cursor[d4.x], 1);
      bin[ofs[d4.x] + pos] = src[i * 4];
    }
    if (d4.y >= lo && d4.y < hi) {
      int pos = atomicAdd(&cursor[d4.y], 1);
      bin[ofs[d4.y] + pos] = src[i * 4 + 1];
    }
    if (d4.z >= lo && d4.z < hi) {
      int pos = atomicAdd(&cursor[d4.z], 1);
      bin[ofs[d4.z] + pos] = src[i * 4 + 2];
    }
    if (d4.w >= lo && d4.w < hi) {
      int pos = atomicAdd(&cursor[d4.w], 1);
      bin[ofs[d4.w] + pos] = src[i * 4 + 3];
    }
  }
  if (blockIdx.x == 0 && threadIdx.x < (E & 3)) {  // tail, any region
    int e = (E4 << 2) + threadIdx.x;
    int d = dst[e];
    int pos = atomicAdd(&cursor[d], 1);
    bin[ofs[d] + pos] = src[e];
  }
}

// ---------- fused GEMM: hA16 = bf16(x @ W1) via MFMA, skipout = x @ W_skip fp32 ----
// W1 converted/transposed into LDS per block (L2-resident, ~free); x rows are
// read once and reused for both products.
__global__ __launch_bounds__(256) void k_gemm1(const float* __restrict__ x,
                                               const float* __restrict__ W1,
                                               const float* __restrict__ W_skip,
                                               unsigned short* __restrict__ hA16,
                                               float* __restrict__ skipout, int N) {
  __shared__ __align__(16) unsigned short Bs[128][136];  // [n][k] bf16 of W1^T
  __shared__ float Ws[256];                              // W_skip [128][2]
  const int t = threadIdx.x;
#pragma unroll
  for (int it = 0; it < 8; ++it) {
    int idx = t + it * 256;            // 2048 chunks of 8
    int n = idx >> 4, c = (idx & 15) * 8;
    unsigned short tmp[8];
#pragma unroll
    for (int j = 0; j < 8; ++j) tmp[j] = f2bf(W1[(c + j) * 128 + n]);
    *(uint4*)&Bs[n][c] = *(uint4*)tmp;
  }
  Ws[t] = W_skip[t];
  __syncthreads();

  const int lane = t & 63, w = t >> 6;
  const int m = lane & 15, q = lane >> 4;
  const int grow = blockIdx.x * 64 + w * 16 + m;
  const bool valid = grow < N;
  const float* xp = &x[(size_t)(valid ? grow : 0) * 128];

  f32x4 acc[8];
#pragma unroll
  for (int nt = 0; nt < 8; ++nt) acc[nt] = (f32x4){0.f, 0.f, 0.f, 0.f};
  float sk0 = 0.f, sk1 = 0.f;

#pragma unroll
  for (int ks = 0; ks < 4; ++ks) {
    short8 a;
    const int kb = ks * 32 + q * 8;
    if (valid) {
      const float* p = xp + kb;
      float4 f0 = *(const float4*)p;
      float4 f1 = *(const float4*)(p + 4);
      a[0] = (short)f2bf(f0.x); a[1] = (short)f2bf(f0.y);
      a[2] = (short)f2bf(f0.z); a[3] = (short)f2bf(f0.w);
      a[4] = (short)f2bf(f1.x); a[5] = (short)f2bf(f1.y);
      a[6] = (short)f2bf(f1.z); a[7] = (short)f2bf(f1.w);
      // fp32 skip-GEMM partials on the same data
      sk0 += f0.x * Ws[(kb + 0) * 2] + f0.y * Ws[(kb + 1) * 2] +
             f0.z * Ws[(kb + 2) * 2] + f0.w * Ws[(kb + 3) * 2] +
             f1.x * Ws[(kb + 4) * 2] + f1.y * Ws[(kb + 5) * 2] +
             f1.z * Ws[(kb + 6) * 2] + f1.w * Ws[(kb + 7) * 2];
      sk1 += f0.x * Ws[(kb + 0) * 2 + 1] + f0.y * Ws[(kb + 1) * 2 + 1] +
             f0.z * Ws[(kb + 2) * 2 + 1] + f0.w * Ws[(kb + 3) * 2 + 1] +
             f1.x * Ws[(kb + 4) * 2 + 1] + f1.y * Ws[(kb + 5) * 2 + 1] +
             f1.z * Ws[(kb + 6) * 2 + 1] + f1.w * Ws[(kb + 7) * 2 + 1];
    } else {
      a = (short8)0;
    }
#pragma unroll
    for (int nt = 0; nt < 8; ++nt) {
      short8 b = *(const short8*)&Bs[nt * 16 + m][ks * 32 + q * 8];
      acc[nt] = __builtin_amdgcn_mfma_f32_16x16x32_bf16(a, b, acc[nt], 0, 0, 0);
    }
  }

  // reduce skip partials across the 4 q-lanes of this row (lanes m, m+16, m+32, m+48)
  sk0 += __shfl_xor(sk0, 16); sk0 += __shfl_xor(sk0, 32);
  sk1 += __shfl_xor(sk1, 16); sk1 += __shfl_xor(sk1, 32);
  if (valid && q == 0) *(float2*)&skipout[grow * 2] = make_float2(sk0, sk1);

  // C/D layout: col = lane&15, row = (lane>>4)*4 + reg
  const int orow = blockIdx.x * 64 + w * 16 + q * 4;
#pragma unroll
  for (int nt = 0; nt < 8; ++nt) {
    int col = nt * 16 + m;
#pragma unroll
    for (int rg = 0; rg < 4; ++rg) {
      int rr = orow + rg;
      if (rr < N) hA16[(size_t)rr * 128 + col] = f2bf(acc[nt][rg]);
    }
  }
}

// ---------- fused layer-1: CSR gather (bf16 hA) + self-loop + bias + relu + @W2 ----
__global__ __launch_bounds__(256) void k_gather1(const int* __restrict__ ofs,
                                                 const int* __restrict__ cnt,
                                                 const int* __restrict__ bin,
                                                 const float* __restrict__ dinv,
                                                 const unsigned int* __restrict__ hA,
                                                 const float* __restrict__ b1,
                                                 const float* __restrict__ W2,
                                                 float* __restrict__ t2base, int N) {
  int d = blockIdx.x * 4 + (threadIdx.x >> 6);
  if (d >= N) return;
  const int lane = threadIdx.x & 63;
  const int beg = ofs[d], end = beg + cnt[d];
  float ax = 0.f, ay = 0.f;
  int e = beg;
  for (; e + 7 < end; e += 8) {
    int s0 = bin[e],     s1 = bin[e + 1], s2 = bin[e + 2], s3 = bin[e + 3];
    int s4 = bin[e + 4], s5 = bin[e + 5], s6 = bin[e + 6], s7 = bin[e + 7];
    float w0 = dinv[s0], w1 = dinv[s1], w2 = dinv[s2], w3 = dinv[s3];
    float w4 = dinv[s4], w5 = dinv[s5], w6 = dinv[s6], w7 = dinv[s7];
    unsigned int v0 = hA[(size_t)s0 * 64 + lane];
    unsigned int v1 = hA[(size_t)s1 * 64 + lane];
    unsigned int v2 = hA[(size_t)s2 * 64 + lane];
    unsigned int v3 = hA[(size_t)s3 * 64 + lane];
    unsigned int v4 = hA[(size_t)s4 * 64 + lane];
    unsigned int v5 = hA[(size_t)s5 * 64 + lane];
    unsigned int v6 = hA[(size_t)s6 * 64 + lane];
    unsigned int v7 = hA[(size_t)s7 * 64 + lane];
    ax += w0 * bf2f(v0 & 0xffff) + w1 * bf2f(v1 & 0xffff) +
          w2 * bf2f(v2 & 0xffff) + w3 * bf2f(v3 & 0xffff) +
          w4 * bf2f(v4 & 0xffff) + w5 * bf2f(v5 & 0xffff) +
          w6 * bf2f(v6 & 0xffff) + w7 * bf2f(v7 & 0xffff);
    ay += w0 * bf2f(v0 >> 16) + w1 * bf2f(v1 >> 16) +
          w2 * bf2f(v2 >> 16) + w3 * bf2f(v3 >> 16) +
          w4 * bf2f(v4 >> 16) + w5 * bf2f(v5 >> 16) +
          w6 * bf2f(v6 >> 16) + w7 * bf2f(v7 >> 16);
  }
  for (; e < end; ++e) {
    int s = bin[e];
    float w = dinv[s];
    unsigned int v = hA[(size_t)s * 64 + lane];
    ax += w * bf2f(v & 0xffff);
    ay += w * bf2f(v >> 16);
  }
  const float dd = dinv[d];
  unsigned int vs = hA[(size_t)d * 64 + lane];
  float v0 = ax * dd + bf2f(vs & 0xffff) * dd * dd + b1[lane * 2];
  float v1 = ay * dd + bf2f(vs >> 16) * dd * dd + b1[lane * 2 + 1];
  v0 = fmaxf(v0, 0.f);
  v1 = fmaxf(v1, 0.f);
  float4 w2v = *(const float4*)&W2[lane * 4];
  float p0 = v0 * w2v.x + v1 * w2v.z;
  float p1 = v0 * w2v.y + v1 * w2v.w;
#pragma unroll
  for (int off = 32; off > 0; off >>= 1) {
    p0 += __shfl_down(p0, off);
    p1 += __shfl_down(p1, off);
  }
  if (lane == 0) *(float2*)&t2base[d * 2] = make_float2(p0, p1);
}

// ---------- final: layer-2 CSR gather + self-loop + b2 + skipout + b_skip ----------
__global__ __launch_bounds__(256) void k_final(const float* __restrict__ b_skip,
                                               const float* __restrict__ b2,
                                               const float* __restrict__ t2base,
                                               const float* __restrict__ skipout,
                                               const float* __restrict__ dinv,
                                               const int* __restrict__ ofs,
                                               const int* __restrict__ cnt,
                                               const int* __restrict__ bin,
                                               float* __restrict__ out, int N) {
  int i = blockIdx.x * 4 + (threadIdx.x >> 6);
  if (i >= N) return;
  const int lane = threadIdx.x & 63;
  const int beg = ofs[i], end = beg + cnt[i];
  float g0 = 0.f, g1 = 0.f;
  for (int e = beg + lane; e < end; e += 64) {
    int s = bin[e];
    float w = dinv[s];
    float2 t = *(const float2*)&t2base[s * 2];
    g0 += w * t.x; g1 += w * t.y;
  }
#pragma unroll
  for (int off = 32; off > 0; off >>= 1) {
    g0 += __shfl_down(g0, off);
    g1 += __shfl_down(g1, off);
  }
  if (lane == 0) {
    float di = dinv[i], d2 = di * di;
    float2 ts = *(const float2*)&t2base[i * 2];
    float2 sk = *(const float2*)&skipout[i * 2];
    float o0 = g0 * di + ts.x * d2 + b2[0] + sk.x + b_skip[0];
    float o1 = g1 * di + ts.y * d2 + b2[1] + sk.y + b_skip[1];
    *(float2*)&out[i * 2] = make_float2(o0, o1);
  }
}

extern "C" void kernel_launch(void* const* d_in, const int* in_sizes, int n_in,
                              void* d_out, int out_size, void* d_ws, size_t ws_size,
                              hipStream_t stream) {
  const float* x      = (const float*)d_in[0];
  const int*   edges  = (const int*)d_in[1];
  const float* W1     = (const float*)d_in[2];
  const float* b1     = (const float*)d_in[3];
  const float* W2     = (const float*)d_in[4];
  const float* b2     = (const float*)d_in[5];
  const float* W_skip = (const float*)d_in[6];
  const float* b_skip = (const float*)d_in[7];
  float* out = (float*)d_out;

  const int N = NN;
  const int E = in_sizes[1] / 2;
  const int* src = edges;
  const int* dst = edges + E;

  // ws: [cnt N][total 4][cursor N][ofs N+4][dinv N][bin E][t2base 2N][skipout 2N]
  //     [hA16 128N shorts]
  int*   cnt     = (int*)d_ws;
  int*   total   = cnt + N;
  int*   cursor  = total + 4;
  int*   ofs     = cursor + N;
  float* dinv    = (float*)(ofs + N + 4);
  int*   bin     = (int*)(dinv + N);
  float* t2base  = (float*)(bin + E);
  float* skipout = t2base + 2 * (size_t)N;
  unsigned short* hA16 = (unsigned short*)(skipout + 2 * (size_t)N);

  hipMemsetAsync(cnt, 0, ((size_t)N + 4) * sizeof(int), stream);  // cnt + total

  k_deg<<<(E / 4 + 256) / 256, 256, 0, stream>>>(dst, E, cnt);
  k_alloc<<<(N + 255) / 256, 256, 0, stream>>>(cnt, ofs, dinv, cursor, total, N);
  k_binfill2<<<1024, 256, 0, stream>>>(src, dst, E, ofs, cursor, bin);
  k_gemm1<<<(N + 63) / 64, 256, 0, stream>>>(x, W1, W_skip, hA16, skipout, N);
  k_gather1<<<(N + 3) / 4, 256, 0, stream>>>(ofs, cnt, bin, dinv,
                                             (const unsigned int*)hA16, b1, W2,
                                             t2base, N);
  k_final<<<(N + 3) / 4, 256, 0, stream>>>(b_skip, b2, t2base, skipout, dinv, ofs,
                                           cnt, bin, out, N);
}